// Round 3
// baseline (134.552 us; speedup 1.0000x reference)
//
#include <hip/hip_runtime.h>
#include <math.h>

namespace {

typedef float f32x4 __attribute__((ext_vector_type(4)));

constexpr int A = 4;
constexpr int H = 2048;
constexpr int BLK = 512;            // 1 f32x4 chunk per thread (512*4 = 2048 = H)
constexpr float EPSV = 1e-6f;
constexpr float CLIPV = 120.0f;

__device__ __forceinline__ float clipv(float v) {
    return fminf(fmaxf(v, -CLIPV), CLIPV);
}

__global__ __launch_bounds__(BLK, 4) void altup_fused(
    const float* __restrict__ hs,        // [A,T,H]
    const float* __restrict__ act,       // [T,H]
    const float* __restrict__ rnw,       // [H]
    const float* __restrict__ w_router,  // [A,H]
    const float* __restrict__ w_pred,    // [16,4]
    const float* __restrict__ w_corr,    // [4,4]
    const float* __restrict__ oscale,    // [H]
    float* __restrict__ out,             // corrected [A,T,H] ++ output [T,H]
    int T)
{
    const int t   = blockIdx.x;
    const int tid = threadIdx.x;
    const size_t TH = (size_t)T * H;
    const size_t rowOff = (size_t)t * H;
    const int h = tid * 4;

    // ---- issue ALL big-stream loads up front (read-once -> non-temporal) ----
    const f32x4 x0 = __builtin_nontemporal_load((const f32x4*)(hs + rowOff + h));
    const f32x4 av = __builtin_nontemporal_load((const f32x4*)(act + rowOff + h));
    const f32x4 x1 = __builtin_nontemporal_load((const f32x4*)(hs + 1 * TH + rowOff + h));
    const f32x4 x2 = __builtin_nontemporal_load((const f32x4*)(hs + 2 * TH + rowOff + h));
    const f32x4 x3 = __builtin_nontemporal_load((const f32x4*)(hs + 3 * TH + rowOff + h));
    // block-shared small arrays: normal cached loads (L1/L2-resident)
    const f32x4 rv = *(const f32x4*)(rnw + h);
    const f32x4 sv = *(const f32x4*)(oscale + h);
    const f32x4 w0 = *(const f32x4*)(w_router + 0 * H + h);
    const f32x4 w1 = *(const f32x4*)(w_router + 1 * H + h);
    const f32x4 w2 = *(const f32x4*)(w_router + 2 * H + h);
    const f32x4 w3 = *(const f32x4*)(w_router + 3 * H + h);

    // ---- phase 1: 10 partial sums ----
    float part[10];
#pragma unroll
    for (int i = 0; i < 10; ++i) part[i] = 0.f;
#pragma unroll
    for (int k = 0; k < 4; ++k) {
        const float x = x0[k], a = av[k], r = rv[k];
        part[0] = fmaf(x, x, part[0]);
        part[5] = fmaf(a, a, part[5]);
        const float xr = x * r;
        const float ar = a * r;
        part[1] = fmaf(xr, w0[k], part[1]);
        part[2] = fmaf(xr, w1[k], part[2]);
        part[3] = fmaf(xr, w2[k], part[3]);
        part[4] = fmaf(xr, w3[k], part[4]);
        part[6] = fmaf(ar, w0[k], part[6]);
        part[7] = fmaf(ar, w1[k], part[7]);
        part[8] = fmaf(ar, w2[k], part[8]);
        part[9] = fmaf(ar, w3[k], part[9]);
    }

    // ---- wave(64) shuffle reduce, then 8-wave combine via LDS ----
#pragma unroll
    for (int off = 32; off >= 1; off >>= 1) {
#pragma unroll
        for (int i = 0; i < 10; ++i) part[i] += __shfl_down(part[i], off, 64);
    }

    __shared__ float red[10][8];     // [sum][wave] -> vectorizable broadcast reads
    const int wave = tid >> 6;
    const int lane = tid & 63;
    if (lane == 0) {
#pragma unroll
        for (int i = 0; i < 10; ++i) red[i][wave] = part[i];
    }
    __syncthreads();

    float sums[10];
#pragma unroll
    for (int i = 0; i < 10; ++i) {
        const f32x4 lo = *(const f32x4*)&red[i][0];
        const f32x4 hi = *(const f32x4*)&red[i][4];
        sums[i] = ((lo[0] + lo[1]) + (lo[2] + lo[3])) +
                  ((hi[0] + hi[1]) + (hi[2] + hi[3]));
    }

    // ---- phase 2: scalar coefficients (redundant per thread) ----
    const float invH = 1.0f / (float)H;
    const float sp = rsqrtf(sums[0] * invH + EPSV) * invH;
    const float sc = rsqrtf(sums[5] * invH + EPSV) * invH;
    float mp[4], mc[4];
#pragma unroll
    for (int j = 0; j < 4; ++j) {
        mp[j] = tanhf(sums[1 + j] * sp);
        mc[j] = tanhf(sums[6 + j] * sc);
    }

    // coef[a][b] = sum_j mp[j]*clip(w_pred[b*4+a, j])  (reshape+transpose folded)
    float coef[4][4];
#pragma unroll
    for (int b = 0; b < 4; ++b) {
#pragma unroll
        for (int a = 0; a < 4; ++a) {
            float s = 0.f;
#pragma unroll
            for (int j = 0; j < 4; ++j)
                s = fmaf(mp[j], clipv(w_pred[(b * 4 + a) * A + j]), s);
            coef[a][b] = s;
        }
    }
    float cc[4];
#pragma unroll
    for (int a = 0; a < 4; ++a) {
        float s = 1.0f;
#pragma unroll
        for (int j = 0; j < 4; ++j)
            s = fmaf(mc[j], clipv(w_corr[a * A + j]), s);
        cc[a] = s;
    }

    // ---- phase 3: pointwise predict/correct/scale; non-temporal stores ----
    f32x4 co[4], ov;
#pragma unroll
    for (int k = 0; k < 4; ++k) {
        const float xs4[4] = {x0[k], x1[k], x2[k], x3[k]};
        float pr[4];
#pragma unroll
        for (int b = 0; b < 4; ++b) {
            float s = xs4[b];
#pragma unroll
            for (int a = 0; a < 4; ++a)
                s = fmaf(xs4[a], coef[a][b], s);
            pr[b] = s;
        }
        const float innov = av[k] - pr[0];
#pragma unroll
        for (int a = 0; a < 4; ++a)
            co[a][k] = fmaf(innov, cc[a], pr[a]);
        ov[k] = co[0][k] * sv[k];
    }
#pragma unroll
    for (int a = 0; a < 4; ++a)
        __builtin_nontemporal_store(co[a], (f32x4*)(out + (size_t)a * TH + rowOff + h));
    __builtin_nontemporal_store(ov, (f32x4*)(out + (size_t)A * TH + rowOff + h));
}

}  // namespace

extern "C" void kernel_launch(void* const* d_in, const int* in_sizes, int n_in,
                              void* d_out, int out_size, void* d_ws, size_t ws_size,
                              hipStream_t stream) {
    const float* hs       = (const float*)d_in[0];
    const float* act      = (const float*)d_in[1];
    const float* rnw      = (const float*)d_in[2];
    const float* w_router = (const float*)d_in[3];
    const float* w_pred   = (const float*)d_in[4];
    const float* w_corr   = (const float*)d_in[5];
    const float* oscale   = (const float*)d_in[6];
    float* out = (float*)d_out;

    const int T = in_sizes[1] / H;  // activated is [T,H]

    altup_fused<<<dim3(T), dim3(BLK), 0, stream>>>(
        hs, act, rnw, w_router, w_pred, w_corr, oscale, out, T);
}

// Round 4
// 127.283 us; speedup vs baseline: 1.0571x; 1.0571x over previous
//
#include <hip/hip_runtime.h>
#include <math.h>

namespace {

typedef float f32x4 __attribute__((ext_vector_type(4)));

constexpr int A = 4;
constexpr int H = 2048;
constexpr int BLK = 256;   // 2 f32x4 chunks per thread
constexpr int TPB = 4;     // tokens per block (software pipeline depth 2)
constexpr float EPSV = 1e-6f;
constexpr float CLIPV = 120.0f;

__device__ __forceinline__ float clipv(float v) {
    return fminf(fmaxf(v, -CLIPV), CLIPV);
}

__global__ __launch_bounds__(BLK, 2) void altup_fused(
    const float* __restrict__ hs,        // [A,T,H]
    const float* __restrict__ act,       // [T,H]
    const float* __restrict__ rnw,       // [H]
    const float* __restrict__ w_router,  // [A,H]
    const float* __restrict__ w_pred,    // [16,4]
    const float* __restrict__ w_corr,    // [4,4]
    const float* __restrict__ oscale,    // [H]
    float* __restrict__ out,             // corrected [A,T,H] ++ output [T,H]
    int T, int G)                        // G = gridDim.x = T/TPB
{
    const int b   = blockIdx.x;
    const int tid = threadIdx.x;
    const size_t TH = (size_t)T * H;
    const int hofs[2] = {tid * 4, 1024 + tid * 4};

    // ---- block-invariant weights: load ONCE per block (L1/L2-resident) ----
    f32x4 rv[2], sv[2], wr[4][2];
#pragma unroll
    for (int c = 0; c < 2; ++c) {
        const int h = hofs[c];
        rv[c] = *(const f32x4*)(rnw + h);
        sv[c] = *(const f32x4*)(oscale + h);
#pragma unroll
        for (int j = 0; j < 4; ++j)
            wr[j][c] = *(const f32x4*)(w_router + j * H + h);
    }

    // stream registers: [parity][chunk][{x0,av,x1,x2,x3}]
    f32x4 s[2][2][5];

    // issue a token's 10 non-temporal stream loads into parity slot p
#define LDTOK(i, p)                                                              \
    {                                                                            \
        const size_t ro = (size_t)(b + (i) * G) * H;                             \
        _Pragma("unroll")                                                        \
        for (int c = 0; c < 2; ++c) {                                            \
            const int h = hofs[c];                                               \
            s[p][c][0] = __builtin_nontemporal_load((const f32x4*)(hs + ro + h));            \
            s[p][c][1] = __builtin_nontemporal_load((const f32x4*)(act + ro + h));           \
            s[p][c][2] = __builtin_nontemporal_load((const f32x4*)(hs + 1 * TH + ro + h));   \
            s[p][c][3] = __builtin_nontemporal_load((const f32x4*)(hs + 2 * TH + ro + h));   \
            s[p][c][4] = __builtin_nontemporal_load((const f32x4*)(hs + 3 * TH + ro + h));   \
        }                                                                        \
    }

    __shared__ float red[2][10][BLK / 64];
    const int wave = tid >> 6;
    const int lane = tid & 63;
    const float invH = 1.0f / (float)H;

    LDTOK(0, 0);

#pragma unroll
    for (int i = 0; i < TPB; ++i) {
        const int p = i & 1;
        // prefetch next token's streams BEFORE touching current token's data:
        // its HBM latency hides under this token's reduce/tanh bubble.
        if (i + 1 < TPB) LDTOK(i + 1, p ^ 1);

        // ---- phase 1: 10 partial sums over current token ----
        float part[10];
#pragma unroll
        for (int q = 0; q < 10; ++q) part[q] = 0.f;
#pragma unroll
        for (int c = 0; c < 2; ++c) {
#pragma unroll
            for (int k = 0; k < 4; ++k) {
                const float x = s[p][c][0][k], a = s[p][c][1][k], r = rv[c][k];
                part[0] = fmaf(x, x, part[0]);
                part[5] = fmaf(a, a, part[5]);
                const float xr = x * r;
                const float ar = a * r;
                part[1] = fmaf(xr, wr[0][c][k], part[1]);
                part[2] = fmaf(xr, wr[1][c][k], part[2]);
                part[3] = fmaf(xr, wr[2][c][k], part[3]);
                part[4] = fmaf(xr, wr[3][c][k], part[4]);
                part[6] = fmaf(ar, wr[0][c][k], part[6]);
                part[7] = fmaf(ar, wr[1][c][k], part[7]);
                part[8] = fmaf(ar, wr[2][c][k], part[8]);
                part[9] = fmaf(ar, wr[3][c][k], part[9]);
            }
        }

        // ---- wave(64) shuffle reduce + 4-wave LDS combine (parity buffer) ----
#pragma unroll
        for (int off = 32; off >= 1; off >>= 1) {
#pragma unroll
            for (int q = 0; q < 10; ++q) part[q] += __shfl_down(part[q], off, 64);
        }
        if (lane == 0) {
#pragma unroll
            for (int q = 0; q < 10; ++q) red[p][q][wave] = part[q];
        }
        __syncthreads();

        float sums[10];
#pragma unroll
        for (int q = 0; q < 10; ++q) {
            const f32x4 v = *(const f32x4*)&red[p][q][0];
            sums[q] = (v[0] + v[1]) + (v[2] + v[3]);
        }

        // ---- phase 2: scalar coefficients (redundant per thread) ----
        const float spn = rsqrtf(sums[0] * invH + EPSV) * invH;
        const float scn = rsqrtf(sums[5] * invH + EPSV) * invH;
        float mp[4], mc[4];
#pragma unroll
        for (int j = 0; j < 4; ++j) {
            mp[j] = tanhf(sums[1 + j] * spn);
            mc[j] = tanhf(sums[6 + j] * scn);
        }
        float coef[4][4];
#pragma unroll
        for (int bb = 0; bb < 4; ++bb) {
#pragma unroll
            for (int aa = 0; aa < 4; ++aa) {
                float sacc = 0.f;
#pragma unroll
                for (int j = 0; j < 4; ++j)
                    sacc = fmaf(mp[j], clipv(w_pred[(bb * 4 + aa) * A + j]), sacc);
                coef[aa][bb] = sacc;
            }
        }
        float cc[4];
#pragma unroll
        for (int aa = 0; aa < 4; ++aa) {
            float sacc = 1.0f;
#pragma unroll
            for (int j = 0; j < 4; ++j)
                sacc = fmaf(mc[j], clipv(w_corr[aa * A + j]), sacc);
            cc[aa] = sacc;
        }

        // ---- phase 3: pointwise predict/correct/scale; non-temporal stores ----
        const size_t ro = (size_t)(b + i * G) * H;
#pragma unroll
        for (int c = 0; c < 2; ++c) {
            const int h = hofs[c];
            f32x4 co[4], ov;
#pragma unroll
            for (int k = 0; k < 4; ++k) {
                const float xs4[4] = {s[p][c][0][k], s[p][c][2][k],
                                      s[p][c][3][k], s[p][c][4][k]};
                float pr[4];
#pragma unroll
                for (int bb = 0; bb < 4; ++bb) {
                    float sacc = xs4[bb];
#pragma unroll
                    for (int aa = 0; aa < 4; ++aa)
                        sacc = fmaf(xs4[aa], coef[aa][bb], sacc);
                    pr[bb] = sacc;
                }
                const float innov = s[p][c][1][k] - pr[0];
#pragma unroll
                for (int aa = 0; aa < 4; ++aa)
                    co[aa][k] = fmaf(innov, cc[aa], pr[aa]);
                ov[k] = co[0][k] * sv[c][k];
            }
#pragma unroll
            for (int aa = 0; aa < 4; ++aa)
                __builtin_nontemporal_store(co[aa], (f32x4*)(out + (size_t)aa * TH + ro + h));
            __builtin_nontemporal_store(ov, (f32x4*)(out + (size_t)A * TH + ro + h));
        }
    }
#undef LDTOK
}

}  // namespace

extern "C" void kernel_launch(void* const* d_in, const int* in_sizes, int n_in,
                              void* d_out, int out_size, void* d_ws, size_t ws_size,
                              hipStream_t stream) {
    const float* hs       = (const float*)d_in[0];
    const float* act      = (const float*)d_in[1];
    const float* rnw      = (const float*)d_in[2];
    const float* w_router = (const float*)d_in[3];
    const float* w_pred   = (const float*)d_in[4];
    const float* w_corr   = (const float*)d_in[5];
    const float* oscale   = (const float*)d_in[6];
    float* out = (float*)d_out;

    const int T = in_sizes[1] / H;  // activated is [T,H]
    const int G = T / TPB;          // 2048 blocks for T=8192

    altup_fused<<<dim3(G), dim3(BLK), 0, stream>>>(
        hs, act, rnw, w_router, w_pred, w_corr, oscale, out, T, G);
}